// Round 2
// baseline (334.400 us; speedup 1.0000x reference)
//
#include <hip/hip_runtime.h>

#define B_ 64
#define L_ 196
#define D_ 2048
#define I_ 512
#define M_ (B_*L_)   // 12544

typedef __attribute__((ext_vector_type(8))) short bf16x8;
typedef __attribute__((ext_vector_type(4))) float f32x4;
typedef unsigned short u16;

__device__ __forceinline__ u16 f2bf(float x){
  unsigned u = __float_as_uint(x);
  u += 0x7fffu + ((u >> 16) & 1u);
  return (u16)(u >> 16);
}

__device__ __forceinline__ void gld16(const void* g, void* l){
  __builtin_amdgcn_global_load_lds(
      (const __attribute__((address_space(1))) void*)g,
      (__attribute__((address_space(3))) void*)l, 16, 0, 0);
}

// gfx9 waitcnt imm: vmcnt[3:0]=bits3:0, expcnt=bits6:4, lgkmcnt=bits11:8, vmcnt[5:4]=bits15:14
template<int N> __device__ __forceinline__ void wait_vm(){
  __builtin_amdgcn_s_waitcnt((N&15) | ((N&48)<<10) | (7<<4) | (15<<8));
}
__device__ __forceinline__ void wait_lgkm0(){
  __builtin_amdgcn_s_waitcnt(15 | (48<<10) | (7<<4));   // vmcnt=63 (no wait), lgkmcnt=0
}
template<int N> __device__ __forceinline__ void wait_lgkm(){
  __builtin_amdgcn_s_waitcnt(15 | (48<<10) | (7<<4) | ((N&15)<<8));
}
__device__ __forceinline__ void bar(){
  asm volatile("" ::: "memory");
  __builtin_amdgcn_s_barrier();
  asm volatile("" ::: "memory");
}
__device__ __forceinline__ void fence_sched(){
  __builtin_amdgcn_sched_barrier(0);
}

// fp32 -> bf16, n4 = count/4
__global__ void cvt_bf16_kernel(const float* __restrict__ in, u16* __restrict__ out, int n4){
  int i = blockIdx.x*blockDim.x + threadIdx.x;
  int stride = gridDim.x*blockDim.x;
  for (; i < n4; i += stride){
    float4 v = ((const float4*)in)[i];
    ushort4 o;
    o.x = f2bf(v.x); o.y = f2bf(v.y); o.z = f2bf(v.z); o.w = f2bf(v.w);
    ((ushort4*)out)[i] = o;
  }
}

// in: [R,C] fp32 row-major  ->  out: [C,R] bf16 row-major
__global__ void transpose_cvt_kernel(const float* __restrict__ in, u16* __restrict__ out, int R, int C){
  __shared__ float tile[32][33];
  int c0 = blockIdx.x*32, r0 = blockIdx.y*32;
  int tx = threadIdx.x, ty = threadIdx.y; // blockDim (32,8)
  for (int i=0;i<32;i+=8)
    tile[ty+i][tx] = in[(size_t)(r0+ty+i)*C + c0 + tx];
  __syncthreads();
  for (int i=0;i<32;i+=8)
    out[(size_t)(c0+ty+i)*R + r0 + tx] = f2bf(tile[tx][ty+i]);
}

// hs[b][n] = b_h[n] + sum_k hidden[b][k]*W_h[k][n].  k-split over 4 groups of 128.
__launch_bounds__(256)
__global__ void hs_kernel(const float* __restrict__ hidden, const float* __restrict__ Wh,
                          const float* __restrict__ bh, float* __restrict__ hs){
  __shared__ float red[4][64];
  const int nl = threadIdx.x & 63, kg = threadIdx.x >> 6;
  const int n = blockIdx.x*64 + nl, b = blockIdx.y;
  const float* hrow = hidden + b*I_;
  float a0=0.f, a1=0.f;
  #pragma unroll
  for (int k=kg*128; k<kg*128+128; k+=2){
    a0 = fmaf(hrow[k+0], Wh[(size_t)(k+0)*I_ + n], a0);
    a1 = fmaf(hrow[k+1], Wh[(size_t)(k+1)*I_ + n], a1);
  }
  red[kg][nl] = a0 + a1;
  __syncthreads();
  if (kg == 0)
    hs[b*I_ + n] = bh[n] + (red[0][nl]+red[1][nl]) + (red[2][nl]+red[3][nl]);
}

// GEMM1: t = bf16(fv_bf @ WfT^T + b_f + hs[batch])   [M,512]
__launch_bounds__(256)
__global__ void gemm1_kernel(const u16* __restrict__ A, const u16* __restrict__ Bt,
                             const float* __restrict__ bias, const float* __restrict__ hs,
                             u16* __restrict__ outb)
{
  constexpr int K = D_, BK = 64, NIT = K/BK;     // 32
  __shared__ __align__(16) u16 Als[2][64*64];    // 8 KB each
  __shared__ __align__(16) u16 Bls[2][128*64];   // 16 KB each

  const int tid = threadIdx.x, lane = tid&63, wave = tid>>6;
  const int m0 = blockIdx.y*64, n0 = blockIdx.x*128;
  const int q = lane>>4, mr = lane&15;
  const int wrow = (wave&1)*32, wcol = (wave>>1)*64;
  const int lrow = lane>>3, kc = (lane&7)^lrow;  // XOR swizzle (0 conflicts, R3)

  const u16* Ag[2]; int Alo[2];
  #pragma unroll
  for (int u=0;u<2;++u){ int j = wave*2+u; Ag[u] = A + (size_t)(m0 + j*8 + lrow)*K + kc*8; Alo[u] = j*512; }
  const u16* Bg[4]; int Blo[4];
  #pragma unroll
  for (int u=0;u<4;++u){ int j = wave*4+u; Bg[u] = Bt + (size_t)(n0 + j*8 + lrow)*K + kc*8; Blo[u] = j*512; }

  int aoff[2][2], boff[4][2];
  #pragma unroll
  for (int i=0;i<2;i++)
    #pragma unroll
    for (int s=0;s<2;s++){ int R = wrow + i*16 + mr; aoff[i][s] = R*64 + (((s*4+q) ^ (mr&7))*8); }
  #pragma unroll
  for (int j=0;j<4;j++)
    #pragma unroll
    for (int s=0;s<2;s++){ int C = wcol + j*16 + mr; boff[j][s] = C*64 + (((s*4+q) ^ (mr&7))*8); }

  f32x4 acc[2][4];
  #pragma unroll
  for (int i=0;i<2;i++)
    #pragma unroll
    for (int j=0;j<4;j++) acc[i][j] = (f32x4){0.f,0.f,0.f,0.f};

  #pragma unroll
  for (int u=0;u<2;++u) gld16(Ag[u],    &Als[0][Alo[u]]);
  #pragma unroll
  for (int u=0;u<4;++u) gld16(Bg[u],    &Bls[0][Blo[u]]);
  #pragma unroll
  for (int u=0;u<2;++u) gld16(Ag[u]+BK, &Als[1][Alo[u]]);
  #pragma unroll
  for (int u=0;u<4;++u) gld16(Bg[u]+BK, &Bls[1][Blo[u]]);

  for (int i=0;i<NIT;++i){
    if (i+1<NIT) wait_vm<6>(); else wait_vm<0>();  // drain ONLY tile i
    bar();
    const u16* Ab = Als[i&1];
    const u16* Bb = Bls[i&1];
    bf16x8 af[2][2], bg[4][2];
    #pragma unroll
    for (int s=0;s<2;s++){
      #pragma unroll
      for (int i2=0;i2<2;i2++) af[i2][s] = *(const bf16x8*)(Ab + aoff[i2][s]);
      #pragma unroll
      for (int j=0;j<4;j++)    bg[j][s]  = *(const bf16x8*)(Bb + boff[j][s]);
    }
    wait_lgkm0();      // frags in regs
    bar();             // buf[i&1] free
    if (i+2<NIT){
      int k0 = (i+2)*BK;
      #pragma unroll
      for (int u=0;u<2;++u) gld16(Ag[u]+k0, &Als[i&1][Alo[u]]);
      #pragma unroll
      for (int u=0;u<4;++u) gld16(Bg[u]+k0, &Bls[i&1][Blo[u]]);
    }
    #pragma unroll
    for (int s=0;s<2;s++)
      #pragma unroll
      for (int i2=0;i2<2;i2++)
        #pragma unroll
        for (int j=0;j<4;j++)
          acc[i2][j] = __builtin_amdgcn_mfma_f32_16x16x32_bf16(af[i2][s], bg[j][s], acc[i2][j], 0,0,0);
  }

  #pragma unroll
  for (int i2=0;i2<2;i2++){
    #pragma unroll
    for (int j=0;j<4;j++){
      int gcol = n0 + wcol + j*16 + mr;
      float bcol = bias[gcol];
      #pragma unroll
      for (int r=0;r<4;r++){
        int grow = m0 + wrow + i2*16 + q*4 + r;
        int batch = grow / L_;
        outb[(size_t)grow*I_ + gcol] = f2bf(acc[i2][j][r] + bcol + hs[batch*I_ + gcol]);
      }
    }
  }
}

// Fused GEMM2 + softmax + z.  BN=64, 4 waves x 16 cols, K=512, BK=32.
// v3 (v2 de-risked): (a) fv prefetched into 52 regs DURING the K-loop via
//     compiler-visible nontemporal loads (spill-safe, T14 pattern) pinned by
//     sched_barrier fences so the hand-counted vmcnt schedule (5/9/13.../9/0)
//     holds exactly; (b) LDS swizzle ^(row>>2): 4-way bank conflict -> free;
//     (c) ds_read/MFMA interleaved in groups of 4 to cap frag liveness;
//     (d) nontemporal alpha stores; (e) launch_bounds(256,2) — no VGPR cap
//     pressure, zero spill risk.
__launch_bounds__(256, 2)
__global__ void gemm2_fused_kernel(const u16* __restrict__ T, const u16* __restrict__ Wa,
                                   const float* __restrict__ b_a, const float* __restrict__ fv,
                                   float* __restrict__ out)
{
  constexpr int K = I_, BK = 32, NIT = K/BK;     // 16
  __shared__ __align__(16) u16 Als[2][256*32];   // 16 KB each
  __shared__ __align__(16) u16 Bls[2][64*32];    // 4 KB each

  const int tid = threadIdx.x, lane = tid&63, wave = tid>>6;
  const int b = blockIdx.y, n0 = blockIdx.x*64;
  const int q = lane>>4, mr = lane&15;
  const int l16 = lane>>2;
  const int kc4 = ((lane&3) ^ (l16&3) ^ (l16>>2)) & 3;   // full 8-slot spread -> uniform banks

  // A: 16 issues of 16 rows x 32 k; wave takes 4
  const u16* Ag[4]; int Alo[4];
  #pragma unroll
  for (int u=0;u<4;++u){
    int j = wave*4+u;
    int grow = b*L_ + j*16 + l16; if (grow > M_-1) grow = M_-1;   // clamp (masked later)
    Ag[u] = T + (size_t)grow*K + kc4*8; Alo[u] = j*512;
  }
  // B: 4 issues; wave takes 1
  const u16* Bg = Wa + (size_t)(n0 + wave*16 + l16)*K + kc4*8;
  const int  Blo = wave*512;

  const int rsw   = ((mr&3) ^ (mr>>2)) & 3;
  const int abase = mr*32 + (((q ^ rsw)&3)*8);   // + i*512 per frag
  const int col   = n0 + wave*16 + mr;           // this lane's e-column
  const int boff  = (wave*16+mr)*32 + (((q ^ rsw)&3)*8);

  const float* fvB = fv + (size_t)b*L_*D_;
  float fvr[52];

  f32x4 acc[13];
  #pragma unroll
  for (int i=0;i<13;i++) acc[i] = (f32x4){0,0,0,0};

  // preload tiles 0,1 (10 outstanding per wave)
  #pragma unroll
  for (int u=0;u<4;++u) gld16(Ag[u],    &Als[0][Alo[u]]);
  gld16(Bg,    &Bls[0][Blo]);
  #pragma unroll
  for (int u=0;u<4;++u) gld16(Ag[u]+BK, &Als[1][Alo[u]]);
  gld16(Bg+BK, &Bls[1][Blo]);

  // per-wave issue order per iter (fenced): [stage(it+2):5][fv(it):4]
  // drain-only-tile-it waits: it=0:5  it=1:9  it in[2..13]:13  it=14:9  it=15:0
  #pragma unroll
  for (int it=0; it<NIT; ++it){
    if      (it == 0)     wait_vm<5>();
    else if (it == 1)     wait_vm<9>();
    else if (it == NIT-1) wait_vm<0>();
    else if (it == NIT-2) wait_vm<9>();
    else                  wait_vm<13>();
    bar();
    const u16* Ab = Als[it&1];
    const u16* Bb = Bls[it&1];
    bf16x8 bg0 = *(const bf16x8*)(Bb + boff);
    bf16x8 af[13];
    #pragma unroll
    for (int i=0;i<8;++i) af[i] = *(const bf16x8*)(Ab + abase + i*512);
    wait_lgkm<4>(); fence_sched();
    #pragma unroll
    for (int i=0;i<4;++i) acc[i] = __builtin_amdgcn_mfma_f32_16x16x32_bf16(af[i], bg0, acc[i], 0,0,0);
    fence_sched();
    #pragma unroll
    for (int i=8;i<12;++i) af[i] = *(const bf16x8*)(Ab + abase + i*512);
    wait_lgkm<4>(); fence_sched();
    #pragma unroll
    for (int i=4;i<8;++i) acc[i] = __builtin_amdgcn_mfma_f32_16x16x32_bf16(af[i], bg0, acc[i], 0,0,0);
    fence_sched();
    af[12] = *(const bf16x8*)(Ab + abase + 12*512);
    wait_lgkm<1>(); fence_sched();
    #pragma unroll
    for (int i=8;i<12;++i) acc[i] = __builtin_amdgcn_mfma_f32_16x16x32_bf16(af[i], bg0, acc[i], 0,0,0);
    wait_lgkm<0>(); fence_sched();
    bar();             // buf[it&1] free
    if (it+2<NIT){
      int k0 = (it+2)*BK;
      #pragma unroll
      for (int u=0;u<4;++u) gld16(Ag[u]+k0, &Als[it&1][Alo[u]]);
      gld16(Bg+k0, &Bls[it&1][Blo]);
    }
    fence_sched();     // stage ops strictly BEFORE fv loads (vmcnt accounting)
    if (it < 12){
      #pragma unroll
      for (int r=0;r<4;++r)
        fvr[it*4+r] = __builtin_nontemporal_load(&fvB[(size_t)(it*16 + q*4 + r)*D_ + col]);
    } else if (it == 12){
      #pragma unroll
      for (int r=0;r<4;++r){
        int row = 192 + q*4 + r; if (row > L_-1) row = L_-1;   // junk for q>0, masked below
        fvr[48+r] = __builtin_nontemporal_load(&fvB[(size_t)row*D_ + col]);
      }
    }
    fence_sched();     // fv loads stay inside this iteration
    acc[12] = __builtin_amdgcn_mfma_f32_16x16x32_bf16(af[12], bg0, acc[12], 0,0,0);
  }
  fence_sched();   // fvr regs valid (vmcnt(0) at it=15); pin epilogue below

  // ---- fused epilogue: e = acc + b_a; softmax over 196 rows; alpha + z ----
  const bool v12 = (q == 0);                     // frag 12: rows 192..195 valid only for q==0
  float bc = b_a[col];
  #pragma unroll
  for (int i=0;i<13;++i)
    #pragma unroll
    for (int r=0;r<4;++r) acc[i][r] += bc;

  float m = -3.4e38f;
  #pragma unroll
  for (int i=0;i<12;++i)
    #pragma unroll
    for (int r=0;r<4;++r) m = fmaxf(m, acc[i][r]);
  if (v12)
    #pragma unroll
    for (int r=0;r<4;++r) m = fmaxf(m, acc[12][r]);
  m = fmaxf(m, __shfl_xor(m, 16));
  m = fmaxf(m, __shfl_xor(m, 32));

  float s = 0.f;
  #pragma unroll
  for (int i=0;i<12;++i)
    #pragma unroll
    for (int r=0;r<4;++r){ float e = __expf(acc[i][r]-m); acc[i][r] = e; s += e; }
  if (v12)
    #pragma unroll
    for (int r=0;r<4;++r){ float e = __expf(acc[12][r]-m); acc[12][r] = e; s += e; }
  s += __shfl_xor(s, 16);
  s += __shfl_xor(s, 32);
  float inv = 1.f/s;

  float* alpha = out + (size_t)B_*D_ + (size_t)b*L_*D_;
  float z = 0.f;
  #pragma unroll
  for (int i=0;i<12;++i){
    #pragma unroll
    for (int r=0;r<4;++r){
      int row = i*16 + q*4 + r;
      float a = acc[i][r] * inv;
      __builtin_nontemporal_store(a, &alpha[(size_t)row*D_ + col]);
      z = fmaf(a, fvr[i*4+r], z);
    }
  }
  if (v12){
    #pragma unroll
    for (int r=0;r<4;++r){
      int row = 192 + r;
      float a = acc[12][r] * inv;
      __builtin_nontemporal_store(a, &alpha[(size_t)row*D_ + col]);
      z = fmaf(a, fvr[48+r], z);
    }
  }
  z += __shfl_xor(z, 16);
  z += __shfl_xor(z, 32);
  if (q == 0) out[(size_t)b*D_ + col] = z;
}

extern "C" void kernel_launch(void* const* d_in, const int* in_sizes, int n_in,
                              void* d_out, int out_size, void* d_ws, size_t ws_size,
                              hipStream_t stream){
  (void)in_sizes; (void)n_in; (void)out_size; (void)ws_size;
  const float* fv     = (const float*)d_in[0];
  const float* hidden = (const float*)d_in[1];
  const float* W_f    = (const float*)d_in[2];
  const float* b_f    = (const float*)d_in[3];
  const float* W_h    = (const float*)d_in[4];
  const float* b_h    = (const float*)d_in[5];
  const float* W_a    = (const float*)d_in[6];
  const float* b_a    = (const float*)d_in[7];
  float* out = (float*)d_out;

  char* ws = (char*)d_ws;
  u16*   fv_bf = (u16*)ws;                     // 51,380,224 B
  u16*   t_bf  = (u16*)(ws + 51380224);        // 12,845,056 B
  u16*   WfT   = (u16*)(ws + 64225280);        //  2,097,152 B
  u16*   WaT   = (u16*)(ws + 66322432);        //  2,097,152 B
  float* hsbuf = (float*)(ws + 68419584);      //    131,072 B

  cvt_bf16_kernel<<<4096, 256, 0, stream>>>(fv, fv_bf, (B_*L_*D_)/4);
  transpose_cvt_kernel<<<dim3(I_/32, D_/32), dim3(32,8), 0, stream>>>(W_f, WfT, D_, I_);
  transpose_cvt_kernel<<<dim3(D_/32, I_/32), dim3(32,8), 0, stream>>>(W_a, WaT, I_, D_);
  hs_kernel<<<dim3(I_/64, B_), 256, 0, stream>>>(hidden, W_h, b_h, hsbuf);

  gemm1_kernel<<<dim3(I_/128, M_/64), 256, 0, stream>>>(fv_bf, WfT, b_f, hsbuf, t_bf);
  gemm2_fused_kernel<<<dim3(D_/64, B_), 256, 0, stream>>>(t_bf, WaT, b_a, fv, out);
}